// Round 8
// baseline (3941.097 us; speedup 1.0000x reference)
//
#include <hip/hip_runtime.h>

#define BB 64
#define NN 128
#define DD 512
#define NBLK 128
#define NTHR 512
#define GCOLS 24
#define WCS 2064   // u16 per combined-weight col (padded: ~4-way LDS conflict)
#define WXS 1032   // u16 per x-weight col: [Wh 512 | Wl 512 | pad 8]
#define BCS 6656
#define UBE (BB * 2048)   // u16 per ublob ring entry (256 KB)

typedef unsigned short u16;
typedef unsigned int u32;
typedef unsigned long long u64;
typedef __attribute__((ext_vector_type(8))) __bf16 bf16x8;
typedef __attribute__((ext_vector_type(4))) float f32x4;

#define MFMA16(a, b, c) __builtin_amdgcn_mfma_f32_16x16x32_bf16((a), (b), (c), 0, 0, 0)

__device__ __forceinline__ float b2f(u16 u) {
    union { u32 i; float f; } c; c.i = ((u32)u) << 16; return c.f;
}
__device__ __forceinline__ u16 f2b(float f) {
    union { float f; u32 i; } c; c.f = f;
    return (u16)((c.i + 0x7FFFu + ((c.i >> 16) & 1u)) >> 16);
}
__device__ __forceinline__ float sigm(float x) { return 1.f / (1.f + __expf(-x)); }
__device__ __forceinline__ float tanh_(float x) {
    x = fminf(fmaxf(x, -15.f), 15.f);
    float e = __expf(2.f * x);
    return (e - 1.f) / (e + 1.f);
}

// ===== agent-coherent (sc1 / L2-bypass) accessors: RELAXED, fence-free =====
__device__ __forceinline__ float ld_cohf(const float* p) {
    return __hip_atomic_load((float*)p, __ATOMIC_RELAXED, __HIP_MEMORY_SCOPE_AGENT);
}
__device__ __forceinline__ void st_cohf(float* p, float v) {
    __hip_atomic_store(p, v, __ATOMIC_RELAXED, __HIP_MEMORY_SCOPE_AGENT);
}
__device__ __forceinline__ void st_cohu32(u32* p, u32 v) {
    __hip_atomic_store(p, v, __ATOMIC_RELAXED, __HIP_MEMORY_SCOPE_AGENT);
}
__device__ __forceinline__ void st_cohi(int* p, int v) {
    __hip_atomic_store(p, v, __ATOMIC_RELAXED, __HIP_MEMORY_SCOPE_AGENT);
}
__device__ __forceinline__ int ld_cohi(int* p) {
    return __hip_atomic_load(p, __ATOMIC_RELAXED, __HIP_MEMORY_SCOPE_AGENT);
}

// ublob load: CACHED = plain dwordx4 (ring entry never stale); else sc1 pair
template<bool CACHED>
__device__ __forceinline__ bf16x8 ldu16(const u16* p) {
    if constexpr (CACHED) {
        return *(const bf16x8*)p;
    } else {
        union { bf16x8 v; u64 q[2]; } u;
        u.q[0] = __hip_atomic_load((u64*)p,     __ATOMIC_RELAXED, __HIP_MEMORY_SCOPE_AGENT);
        u.q[1] = __hip_atomic_load((u64*)p + 1, __ATOMIC_RELAXED, __HIP_MEMORY_SCOPE_AGENT);
        return u.v;
    }
}

// ===== heavy (fenced) barrier — PROLOGUE ONLY =====
__device__ __forceinline__ void gbar(int* sync, int gen, int blk) {
    __syncthreads();
    int* epoch = sync;
    if (blk == 0) {
        const int t = threadIdx.x;
        int done = (t == 0 || t >= NBLK) ? 1 : 0;
        int* myarr = sync + 256 + t * 16;
        int it = 0;
        for (;;) {
            if (!done) {
                int v = ((it & 15) == 15)
                    ? __hip_atomic_load(myarr, __ATOMIC_ACQUIRE, __HIP_MEMORY_SCOPE_AGENT)
                    : __hip_atomic_load(myarr, __ATOMIC_RELAXED, __HIP_MEMORY_SCOPE_AGENT);
                done = (v >= gen);
            }
            ++it;
            if (__syncthreads_and(done)) break;
            __builtin_amdgcn_s_sleep(1);
        }
        if (t == 0) {
            (void)__hip_atomic_load(sync + 256 + 16, __ATOMIC_ACQUIRE, __HIP_MEMORY_SCOPE_AGENT);
            __hip_atomic_store(epoch, gen, __ATOMIC_RELEASE, __HIP_MEMORY_SCOPE_AGENT);
        }
        __syncthreads();
    } else {
        if (threadIdx.x == 0) {
            __hip_atomic_store(sync + 256 + blk * 16, gen, __ATOMIC_RELEASE, __HIP_MEMORY_SCOPE_AGENT);
            int it = 0;
            for (;;) {
                int v = ((it & 15) == 15)
                    ? __hip_atomic_load(epoch, __ATOMIC_ACQUIRE, __HIP_MEMORY_SCOPE_AGENT)
                    : __hip_atomic_load(epoch, __ATOMIC_RELAXED, __HIP_MEMORY_SCOPE_AGENT);
                ++it;
                if (v >= gen) break;
                __builtin_amdgcn_s_sleep(1);
            }
            (void)__hip_atomic_load(epoch, __ATOMIC_ACQUIRE, __HIP_MEMORY_SCOPE_AGENT);
        }
        __syncthreads();
    }
}

// ===== lite flat barrier (pure relaxed polling) — fallback mode only =====
__device__ __forceinline__ void gbar_lite(int* flags, int gen, int blk,
                                          int nsig, bool sig, bool wait) {
    __syncthreads();
    if (sig && threadIdx.x == 0)
        st_cohi(flags + blk * 32, gen);
    if (wait) {
        const int t = threadIdx.x;
        int done = (t >= nsig) ? 1 : 0;
        int* f = flags + t * 32;
        for (;;) {
            if (!done) done = (ld_cohi(f) >= gen);
            if (__syncthreads_and(done)) break;
            __builtin_amdgcn_s_sleep(2);
        }
    }
    asm volatile("" ::: "memory");
    __builtin_amdgcn_sched_barrier(0);
}

// per-WAVE producer wait with BACKOFF (first check free, then sleep(8)≈512cy
// between polls — cuts standing MALL poll traffic ~8x)
__device__ __forceinline__ void waitA(int* flagsA, int gen, int grp) {
    const int l = threadIdx.x & 63;
    int* f = flagsA + (grp * 16 + (l & 15)) * 32;
    for (;;) {
        int v = ld_cohi(f);
        if (__all(v >= gen)) break;
        __builtin_amdgcn_s_sleep(8);
    }
    asm volatile("" ::: "memory");
    __builtin_amdgcn_sched_barrier(0);
}

// per-wave early PhB-completion signal: drain own stores, count in LDS (monotonic,
// 5 signalers/iter); 5th wave bumps the GLOBAL iteration counter ctrB[i] by 1
// (single-address convergence: owners poll ONE line instead of 128 flags).
__device__ __forceinline__ void sigB2(int* ctrB_i, int* sd, int i, int lane) {
    asm volatile("s_waitcnt vmcnt(0)" ::: "memory");
    if (lane == 0) {
        int old = atomicAdd(sd, 1);
        if (old == 5 * i - 1)
            (void)__hip_atomic_fetch_add(ctrB_i, 1, __ATOMIC_RELAXED, __HIP_MEMORY_SCOPE_AGENT);
    }
}

// single-address wave-uniform counter poll with backoff
__device__ __forceinline__ void ctr_wait(int* p, int tgt) {
    for (;;) {
        if (ld_cohi(p) >= tgt) break;
        __builtin_amdgcn_s_sleep(8);
    }
    asm volatile("" ::: "memory");
    __builtin_amdgcn_sched_barrier(0);
}

// merged gates GEMM: one wave (rt=0..3) computes BOTH column-tiles (cc=lr, lr+8)
template<bool CACHED>
__device__ __forceinline__ void gates_merged(
    const u16* __restrict__ ub, const u16* s_wc, const float* s_gb,
    float* __restrict__ bc, int blk, int rt, int lr, int lq)
{
    const int cc0 = lr, cc1 = lr + 8;
    const u16* w0 = s_wc + cc0 * WCS;
    const u16* w1 = s_wc + cc1 * WCS;
    const u16* arow = ub + (size_t)(rt * 16 + lr) * 2048;
    f32x4 acc0 = {0.f,0.f,0.f,0.f}, acc1 = {0.f,0.f,0.f,0.f};
    #pragma unroll 4
    for (int c = 0; c < 16; ++c) {
        int kk = c * 32 + lq * 8;
        bf16x8 ah = ldu16<CACHED>(arow + kk);
        bf16x8 al = ldu16<CACHED>(arow + 512 + kk);
        bf16x8 wh0 = *(const bf16x8*)(w0 + kk);
        bf16x8 wl0 = *(const bf16x8*)(w0 + 1024 + kk);
        bf16x8 wh1 = *(const bf16x8*)(w1 + kk);
        bf16x8 wl1 = *(const bf16x8*)(w1 + 1024 + kk);
        acc0 = MFMA16(ah, wh0, acc0); acc0 = MFMA16(al, wh0, acc0); acc0 = MFMA16(ah, wl0, acc0);
        acc1 = MFMA16(ah, wh1, acc1); acc1 = MFMA16(al, wh1, acc1); acc1 = MFMA16(ah, wl1, acc1);
    }
    #pragma unroll 4
    for (int c = 0; c < 16; ++c) {
        int kk = c * 32 + lq * 8;
        bf16x8 ah = ldu16<CACHED>(arow + 1024 + kk);
        bf16x8 al = ldu16<CACHED>(arow + 1536 + kk);
        bf16x8 wh0 = *(const bf16x8*)(w0 + 512 + kk);
        bf16x8 wl0 = *(const bf16x8*)(w0 + 1536 + kk);
        bf16x8 wh1 = *(const bf16x8*)(w1 + 512 + kk);
        bf16x8 wl1 = *(const bf16x8*)(w1 + 1536 + kk);
        acc0 = MFMA16(ah, wh0, acc0); acc0 = MFMA16(al, wh0, acc0); acc0 = MFMA16(ah, wl0, acc0);
        acc1 = MFMA16(ah, wh1, acc1); acc1 = MFMA16(al, wh1, acc1); acc1 = MFMA16(ah, wl1, acc1);
    }
    float b0 = s_gb[cc0], b1 = s_gb[cc1];
    int col0 = blk * GCOLS + cc0, col1 = blk * GCOLS + cc1;
    #pragma unroll
    for (int r = 0; r < 4; ++r) {
        size_t row = (size_t)(rt * 16 + lq * 4 + r) * BCS;
        st_cohf(bc + row + 512 + col0, acc0[r] + b0);
        st_cohf(bc + row + 512 + col1, acc1[r] + b1);
    }
}

// x-gates GEMM core (featblob RO-cached)
__device__ __forceinline__ f32x4 x_core(
    int i, const u16* __restrict__ featblob, const u16* s_wxw,
    int task, int lr, int lq, int* ccO)
{
    const int ct = task & 1, rt = task >> 1;
    const int cc = ct * 8 + lr;
    *ccO = cc;
    const u16* wcol = s_wxw + cc * WXS;
    const u16* arow = featblob + (size_t)(i * 64 + rt * 16 + lr) * 1024;
    f32x4 acc = {0.f,0.f,0.f,0.f};
    #pragma unroll 4
    for (int c = 0; c < 16; ++c) {
        int kk = c * 32 + lq * 8;
        bf16x8 ah = *(const bf16x8*)(arow + kk);
        bf16x8 al = *(const bf16x8*)(arow + 512 + kk);
        bf16x8 wh = *(const bf16x8*)(wcol + kk);
        bf16x8 wl = *(const bf16x8*)(wcol + 512 + kk);
        acc = MFMA16(ah, wh, acc); acc = MFMA16(al, wh, acc); acc = MFMA16(ah, wl, acc);
    }
    return acc;
}

__device__ __forceinline__ void x_task(
    int i, const u16* __restrict__ featblob, const u16* s_wxw, const float* s_xb,
    float* __restrict__ bc, int blk, int task, int lr, int lq)
{
    int cc; f32x4 acc = x_core(i, featblob, s_wxw, task, lr, lq, &cc);
    const int rt = task >> 1;
    const int col = blk * GCOLS + cc;
    float bias = s_xb[cc];
    #pragma unroll
    for (int r = 0; r < 4; ++r)
        st_cohf(bc + (size_t)(rt * 16 + lq * 4 + r) * BCS + 3584 + col, acc[r] + bias);
}

// hoisted variant: plain f32 stores into xg[i][row][col]
__device__ __forceinline__ void x_task_xg(
    int i, const u16* __restrict__ featblob, const u16* s_wxw, const float* s_xb,
    float* __restrict__ xg, int blk, int task, int lr, int lq)
{
    int cc; f32x4 acc = x_core(i, featblob, s_wxw, task, lr, lq, &cc);
    const int rt = task >> 1;
    const int col = blk * GCOLS + cc;
    float bias = s_xb[cc];
    #pragma unroll
    for (int r = 0; r < 4; ++r)
        xg[((size_t)i * 64 + rt * 16 + lq * 4 + r) * 3072 + col] = acc[r] + bias;
}

// M GEMM: 16x16 tile per block
template<bool CACHED>
__device__ __forceinline__ void m_task(
    const u16* __restrict__ ub, const u16* __restrict__ WrB,
    float* __restrict__ bc, int blk, int lr, int lq)
{
    const int ct = blk >> 2, rt = blk & 3;
    const int col = ct * 16 + lr;
    const u16* wcol = WrB + (size_t)col * 2048;
    const u16* arow = ub + (size_t)(rt * 16 + lr) * 2048;
    f32x4 acc = {0.f,0.f,0.f,0.f};
    #pragma unroll 4
    for (int c = 0; c < 16; ++c) {
        int kk = c * 32 + lq * 8;
        bf16x8 a0h = ldu16<CACHED>(arow + kk);
        bf16x8 a0l = ldu16<CACHED>(arow + 512 + kk);
        bf16x8 a1h = ldu16<CACHED>(arow + 1024 + kk);
        bf16x8 a1l = ldu16<CACHED>(arow + 1536 + kk);
        bf16x8 w0h = *(const bf16x8*)(wcol + kk);
        bf16x8 w0l = *(const bf16x8*)(wcol + 512 + kk);
        bf16x8 w1h = *(const bf16x8*)(wcol + 1024 + kk);
        bf16x8 w1l = *(const bf16x8*)(wcol + 1536 + kk);
        acc = MFMA16(a0h, w0h, acc); acc = MFMA16(a0l, w0h, acc); acc = MFMA16(a0h, w0l, acc);
        acc = MFMA16(a1h, w1h, acc); acc = MFMA16(a1l, w1h, acc); acc = MFMA16(a1h, w1l, acc);
    }
    #pragma unroll
    for (int r = 0; r < 4; ++r)
        st_cohf(bc + (size_t)(rt * 16 + lq * 4 + r) * BCS + col, acc[r]);
}

__global__ __launch_bounds__(NTHR) void grn_kernel(
    const float* __restrict__ feat, const float* __restrict__ Wi_c, const float* __restrict__ Wh_c,
    const float* __restrict__ bi_c, const float* __restrict__ bh_c,
    const float* __restrict__ Wi_p, const float* __restrict__ Wh_p,
    const float* __restrict__ bi_p, const float* __restrict__ bh_p,
    const float* __restrict__ lin_w, const float* __restrict__ lin_b,
    const float* __restrict__ Wr0, const float* __restrict__ Wr1,
    const int* __restrict__ adj, const int* __restrict__ smask,
    float* __restrict__ out,
    float* __restrict__ q, u16* __restrict__ ublob,
    u16* __restrict__ featblob, float* __restrict__ bc, u16* __restrict__ WrB,
    float* __restrict__ xg, int* __restrict__ sync, int use_ring, int use_xg)
{
    const int t = threadIdx.x, blk = blockIdx.x;
    const int lane = t & 63, wv = t >> 6;
    const int lr = lane & 15, lq = lane >> 4;
    int gen = 0;
    int* flagsA = sync + 4096;   // per-producer flags, 128B-spaced (value = iteration)
    int* flagsB = sync + 8192;   // fallback-mode per-block flags
    int* ctrB   = sync + 12288;  // xg-mode: iteration-indexed completion counters (64B apart)

    __shared__ u16 s_wc[GCOLS * WCS];
    __shared__ __align__(16) char s_wx_raw[GCOLS * WXS * 2];
    __shared__ float s_u0[DD];
    __shared__ float s_ut[DD];
    __shared__ float s_red[NTHR];
    __shared__ float s_hk[NN];
    __shared__ float s_q[NN];
    __shared__ float s_w[NN];
    __shared__ float s_ws[NN];
    __shared__ float s_gb[GCOLS];
    __shared__ float s_xb[GCOLS];
    __shared__ int s_done;       // monotonic PhB-wave completion counter (5/iter)

    u16* s_wxw = (u16*)s_wx_raw;
    float* s_wgf = (float*)s_wx_raw;
    float* s_pu = (float*)s_wx_raw;               // [3][512] masked partials (xg mode)
    float* s_pt = (float*)(s_wx_raw + 6144);      // [3][512] unmasked partials
    float* s_scal = (float*)(s_wx_raw + 12288);   // m_part, denom_p, anew, snew

    const float wkreg = lin_w[DD + t];

    // ================= Ph0: prologue =================
    for (int rr = 0; rr < 64; ++rr) {
        int gr = blk * 64 + rr;
        int bb_ = gr >> 7, nn_ = gr & 127;
        float x = feat[(size_t)gr * DD + t];
        u16 h = f2b(x);
        u16* dst = featblob + (size_t)(nn_ * 64 + bb_) * 1024;
        dst[t] = h;
        dst[512 + t] = f2b(x - b2f(h));
    }
    for (int cc = 0; cc < 4; ++cc) {
        int c = blk * 4 + cc;
        float w0 = Wr0[(size_t)c * DD + t], w1 = Wr1[(size_t)c * DD + t];
        u16 h0 = f2b(w0), h1 = f2b(w1);
        u16* dst = WrB + (size_t)c * 2048;
        dst[t] = h0; dst[512 + t] = f2b(w0 - b2f(h0));
        dst[1024 + t] = h1; dst[1536 + t] = f2b(w1 - b2f(h1));
    }
    {
        float linb = lin_b[0];
        float wqf[8];
        #pragma unroll
        for (int jj = 0; jj < 8; ++jj) wqf[jj] = lin_w[lane * 8 + jj];
        for (int rr = 0; rr < 8; ++rr) {
            int row = blk * 64 + wv * 8 + rr;
            const float* fp = feat + (size_t)row * DD + lane * 8;
            float p = 0.f;
            #pragma unroll
            for (int jj = 0; jj < 8; ++jj) p += fp[jj] * wqf[jj];
            #pragma unroll
            for (int off = 32; off; off >>= 1) p += __shfl_down(p, off, 64);
            if (lane == 0) q[row] = p + linb;
        }
    }
    {
        int jg0 = blk * GCOLS;
        for (int cc = 0; cc < GCOLS; ++cc) {
            int jg = jg0 + cc;
            const float* src = (jg < 1536) ? (Wh_c + (size_t)jg * DD) : (Wi_p + (size_t)(jg - 1536) * DD);
            s_wgf[t * GCOLS + cc] = src[t];
        }
        if (t < GCOLS) {
            int jg = jg0 + t;
            s_gb[t] = (jg < 1536) ? bh_c[jg] : bi_p[jg - 1536];
            s_xb[t] = (jg < 1536) ? bi_c[jg] : bh_p[jg - 1536];
        }
    }
    __syncthreads();
    {
        float acc0[GCOLS], acc1[GCOLS];
        #pragma unroll
        for (int cc = 0; cc < GCOLS; ++cc) { acc0[cc] = 0.f; acc1[cc] = 0.f; }
        for (int j = 0; j < DD; ++j) {
            float wr0 = Wr0[(size_t)j * DD + t];
            float wr1 = Wr1[(size_t)j * DD + t];
            const float* g = s_wgf + j * GCOLS;
            #pragma unroll
            for (int cc = 0; cc < GCOLS; ++cc) {
                float gv = g[cc];
                acc0[cc] += wr0 * gv;
                acc1[cc] += wr1 * gv;
            }
        }
        __syncthreads();
        #pragma unroll
        for (int cc = 0; cc < GCOLS; ++cc) {
            u16 h0 = f2b(acc0[cc]);
            s_wc[cc * WCS + t] = h0;
            s_wc[cc * WCS + 1024 + t] = f2b(acc0[cc] - b2f(h0));
            u16 h1 = f2b(acc1[cc]);
            s_wc[cc * WCS + 512 + t] = h1;
            s_wc[cc * WCS + 1536 + t] = f2b(acc1[cc] - b2f(h1));
        }
    }
    {
        int jx0 = blk * GCOLS;
        for (int cc = 0; cc < GCOLS; ++cc) {
            int jx = jx0 + cc;
            const float* src = (jx < 1536) ? (Wi_c + (size_t)jx * DD) : (Wh_p + (size_t)(jx - 1536) * DD);
            float w = src[t];
            u16 h = f2b(w);
            s_wxw[cc * WXS + t] = h;
            s_wxw[cc * WXS + 512 + t] = f2b(w - b2f(h));
        }
    }
    gbar(sync, ++gen, blk);

    // ================= Ph0x: x-gates row 0 -> bc; (hoisted) all rows -> xg =====
    x_task(0, featblob, s_wxw, s_xb, bc, blk, wv, lr, lq);
    if (use_xg) {
        for (int ii = 0; ii < NN; ++ii)
            x_task_xg(ii, featblob, s_wxw, s_xb, xg, blk, wv, lr, lq);
    }
    if (blk < BB && t < NN) s_q[t] = q[blk * NN + t];
    gbar(sync, ++gen, blk);

    // ================= Ph1: row 0 init =================
    if (blk < BB) {
        if (use_xg) {
            s_pu[t] = 0.f; s_pu[512 + t] = 0.f; s_pu[1024 + t] = 0.f;
            s_pt[t] = 0.f; s_pt[512 + t] = 0.f; s_pt[1024 + t] = 0.f;
            if (t == 0) {
                s_scal[0] = -1e30f; s_scal[1] = 0.f;
                s_scal[2] = (float)adj[((size_t)blk * NN + 1) * NN + 0];
                s_scal[3] = (float)smask[((size_t)blk * NN + 1) * NN + 0];
            }
        }
        const float* bcb = bc + (size_t)blk * BCS;
        float ir = ld_cohf(bcb + 3584 + t), iz = ld_cohf(bcb + 4096 + t), inn = ld_cohf(bcb + 4608 + t);
        float r = sigm(ir + bh_c[t]), z = sigm(iz + bh_c[512 + t]);
        float C = (1.f - z) * tanh_(inn + r * bh_c[1024 + t]);
        float ghr = ld_cohf(bcb + 5120 + t), ghz = ld_cohf(bcb + 5632 + t), ghn = ld_cohf(bcb + 6144 + t);
        float r2 = sigm(bi_p[t] + ghr), z2 = sigm(bi_p[512 + t] + ghz);
        float n2 = tanh_(bi_p[1024 + t] + r2 * ghn);
        float x = feat[(size_t)(blk * NN) * DD + t];
        float P = (1.f - z2) * n2 + z2 * x;
        float Hv = C + P;
        out[(size_t)(blk * NN) * DD + t] = Hv;
        s_red[t] = Hv * wkreg;
        __syncthreads();
        if (wv == 0) {
            float p = 0.f;
            #pragma unroll
            for (int jj = 0; jj < 8; ++jj) p += s_red[lane + 64 * jj];
            #pragma unroll
            for (int off = 32; off; off >>= 1) p += __shfl_down(p, off, 64);
            if (lane == 0) s_hk[0] = p;
        }
    }
    if (t == 0) s_done = 0;
    gbar(sync, ++gen, blk);

    // ================= main scan =================
    for (int i = 1; i < NN; ++i) {
        u16* ub_i = ublob + (size_t)(use_ring ? (NN - 1 - i) : 0) * UBE;

        if (use_xg) {
            int* ctrB_i = ctrB + (size_t)(i - 1) * 16;   // this iteration's counter

            if (blk < BB) {
                // ---- top wait: all 128 blocks' gates+m of iter i-1 done.
                // SINGLE-ADDRESS counter poll (was 128 flags) + backoff. ----
                if (i >= 2) {
                    if (wv == 0) ctr_wait(ctrB + (size_t)(i - 2) * 16, NBLK);
                    __syncthreads();
                }
                // ---- PhA ----
                int j = i - 1;
                float Hv;
                if (i >= 2) {
                    const float* bcb = bc + (size_t)blk * BCS;
                    float Mv = ld_cohf(bcb + t);
                    float hr = ld_cohf(bcb + 512 + t), hz = ld_cohf(bcb + 1024 + t), hn = ld_cohf(bcb + 1536 + t);
                    float gir = ld_cohf(bcb + 2048 + t), giz = ld_cohf(bcb + 2560 + t), gin = ld_cohf(bcb + 3072 + t);
                    const float* xrow = xg + ((size_t)j * 64 + blk) * 3072;
                    float ir = xrow[t], iz = xrow[512 + t], inn = xrow[1024 + t];
                    float ghr = xrow[1536 + t], ghz = xrow[2048 + t], ghn = xrow[2560 + t];
                    float x = feat[(size_t)(blk * NN + j) * DD + t];
                    float r = sigm(ir + hr), z = sigm(iz + hz);
                    float C = (1.f - z) * tanh_(inn + r * hn) + z * Mv;
                    float r2 = sigm(gir + ghr), z2 = sigm(giz + ghz);
                    float P = (1.f - z2) * tanh_(gin + r2 * ghn) + z2 * x;
                    Hv = C + P;
                    out[(size_t)(blk * NN + j) * DD + t] = Hv;
                    s_red[t] = Hv * wkreg;
                } else {
                    Hv = out[(size_t)(blk * NN) * DD + t];
                }
                __syncthreads();
                if (wv == 0) {
                    float hk;
                    if (i >= 2) {
                        float p = 0.f;
                        #pragma unroll
                        for (int jj = 0; jj < 8; ++jj) p += s_red[lane + 64 * jj];
                        #pragma unroll
                        for (int off = 32; off; off >>= 1) p += __shfl_down(p, off, 64);
                        if (lane == 0) s_hk[j] = p;
                        hk = p;
                    } else {
                        hk = s_hk[0];
                    }
                    if (lane == 0) {
                        float m_part = s_scal[0], denom_p = s_scal[1];
                        float anew = s_scal[2], snew = s_scal[3];
                        float alpha = s_q[i] + hk;
                        float m = m_part, e_new = 0.f;
                        if (anew != 0.f) { m = fmaxf(m_part, alpha); e_new = __expf(alpha - m); }
                        float scale = __expf(m_part - m);
                        float inv = 1.f / (denom_p * scale + e_new);
                        s_w[0] = scale * inv;
                        s_w[1] = e_new * snew * inv;
                        s_w[2] = e_new * inv;
                    }
                }
                __syncthreads();
                {
                    float u0p = s_pu[t] + s_pu[512 + t] + s_pu[1024 + t];
                    float utp = s_pt[t] + s_pt[512 + t] + s_pt[1024 + t];
                    float CS = s_w[0], C0 = s_w[1], CT = s_w[2];
                    float U0 = u0p * CS + C0 * Hv;
                    float U1 = (utp * CS + CT * Hv) - U0;
                    u16 h0 = f2b(U0); u16 l0 = f2b(U0 - b2f(h0));
                    u16 h1 = f2b(U1); u16 l1 = f2b(U1 - b2f(h1));
                    u32 p0 = (u32)h0 | ((u32)l0 << 16);
                    u32 p1 = (u32)h1 | ((u32)l1 << 16);
                    u32 q0 = (u32)__shfl_xor((int)p0, 1, 64);
                    u32 q1 = (u32)__shfl_xor((int)p1, 1, 64);
                    u32* ub32 = (u32*)(ub_i + (size_t)blk * 2048);
                    int w = t >> 1;
                    if ((t & 1) == 0) {
                        st_cohu32(ub32 + w,       (p0 & 0xFFFFu) | ((q0 & 0xFFFFu) << 16));
                        st_cohu32(ub32 + 256 + w, (p0 >> 16)     | (q0 & 0xFFFF0000u));
                    } else {
                        st_cohu32(ub32 + 512 + w, (q1 & 0xFFFFu) | ((p1 & 0xFFFFu) << 16));
                        st_cohu32(ub32 + 768 + w, (q1 >> 16)     | (p1 & 0xFFFF0000u));
                    }
                }
                __syncthreads();                          // drain ublob sc1 stores
                if (t == 0) st_cohi(flagsA + blk * 32, i);

                // ---- PhB (owner): gates / m / scan; gates+m signal early ----
                if (wv < 4) {
                    waitA(flagsA, i, wv);
                    if (use_ring) gates_merged<true >(ub_i, s_wc, s_gb, bc, blk, wv, lr, lq);
                    else          gates_merged<false>(ub_i, s_wc, s_gb, bc, blk, wv, lr, lq);
                    sigB2(ctrB_i, &s_done, i, lane);
                } else if (wv == 7) {
                    waitA(flagsA, i, blk & 3);
                    if (use_ring) m_task<true >(ub_i, WrB, bc, blk, lr, lq);
                    else          m_task<false>(ub_i, WrB, bc, blk, lr, lq);
                    sigB2(ctrB_i, &s_done, i, lane);
                } else if (i + 1 < NN) {
                    const int ii = i + 1;
                    const int w = wv - 4;
                    const int* ar = adj + (size_t)(blk * NN + ii) * NN;
                    const int* sr = smask + (size_t)(blk * NN + ii) * NN;
                    int a0 = ar[lane], a1 = ar[lane + 64];
                    int s0 = sr[lane], s1 = sr[lane + 64];
                    float qv = s_q[ii];
                    float al0 = (lane < i && a0 != 0) ? (qv + s_hk[lane]) : -1e30f;
                    float al1 = (lane + 64 < i && a1 != 0) ? (qv + s_hk[lane + 64]) : -1e30f;
                    float m = fmaxf(al0, al1);
                    #pragma unroll
                    for (int off = 32; off; off >>= 1) m = fmaxf(m, __shfl_xor(m, off, 64));
                    float e0 = (al0 > -1e29f) ? __expf(al0 - m) : 0.f;
                    float e1 = (al1 > -1e29f) ? __expf(al1 - m) : 0.f;
                    float es0 = e0 * (float)s0, es1 = e1 * (float)s1;
                    const float* Hb = out + (size_t)blk * NN * DD + lane * 8;
                    f32x4 pa = {0.f,0.f,0.f,0.f}, pb = {0.f,0.f,0.f,0.f};
                    f32x4 ta = {0.f,0.f,0.f,0.f}, tb = {0.f,0.f,0.f,0.f};
                    for (int n = w; n < i; n += 3) {
                        float en  = __shfl((n < 64) ? e0 : e1, n & 63, 64);
                        float esn = __shfl((n < 64) ? es0 : es1, n & 63, 64);
                        f32x4 h0 = *(const f32x4*)(Hb + (size_t)n * DD);
                        f32x4 h1 = *(const f32x4*)(Hb + (size_t)n * DD + 4);
                        pa += esn * h0; pb += esn * h1;
                        ta += en * h0;  tb += en * h1;
                    }
                    *(f32x4*)&s_pu[w * 512 + lane * 8]     = pa;
                    *(f32x4*)&s_pu[w * 512 + lane * 8 + 4] = pb;
                    *(f32x4*)&s_pt[w * 512 + lane * 8]     = ta;
                    *(f32x4*)&s_pt[w * 512 + lane * 8 + 4] = tb;
                    if (w == 0) {
                        float ds = e0 + e1;
                        #pragma unroll
                        for (int off = 32; off; off >>= 1) ds += __shfl_xor(ds, off, 64);
                        if (lane == 0) {
                            s_scal[0] = m; s_scal[1] = ds;
                            s_scal[2] = (float)ar[i];
                            s_scal[3] = (float)sr[i];
                        }
                    }
                    if (w == 2) {
                        const float* fp = feat + (size_t)(blk * NN + i) * DD + lane * 8;
                        f32x4 f0 = *(const f32x4*)fp;
                        f32x4 f1 = *(const f32x4*)(fp + 4);
                        const float* xp = xg + ((size_t)i * 64 + blk) * 3072 + lane * 16;
                        float x0 = xp[0], x1 = xp[1024], x2 = xp[2048];
                        asm volatile("" :: "v"(f0), "v"(f1), "v"(x0), "v"(x1), "v"(x2));
                    }
                }
                // no trailing barrier: next iteration's top wait + __syncthreads covers it
            } else {
                // ---- shard blocks: gates + m only; per-wave, no block barrier.
                // Safety: waitA(gen i) implies row-owners finished PhA(i) incl. their
                // bc(i-1) reads -> overwriting bc is safe. ----
                if (wv < 4) {
                    waitA(flagsA, i, wv);
                    if (use_ring) gates_merged<true >(ub_i, s_wc, s_gb, bc, blk, wv, lr, lq);
                    else          gates_merged<false>(ub_i, s_wc, s_gb, bc, blk, wv, lr, lq);
                    sigB2(ctrB_i, &s_done, i, lane);
                } else if (wv == 7) {
                    waitA(flagsA, i, blk & 3);
                    if (use_ring) m_task<true >(ub_i, WrB, bc, blk, lr, lq);
                    else          m_task<false>(ub_i, WrB, bc, blk, lr, lq);
                    sigB2(ctrB_i, &s_done, i, lane);
                }
            }
        } else {
            // ================= fallback (non-xg) — round-4 path =================
            if (blk < BB) {
                int va0 = 0, va1 = 0, vs0 = 0, vs1 = 0;
                float qv = 0.f;
                if (wv == 0) {
                    const int* ar_ = adj + (size_t)(blk * NN + i) * NN;
                    const int* sr_ = smask + (size_t)(blk * NN + i) * NN;
                    va0 = ar_[lane]; va1 = ar_[lane + 64];
                    vs0 = sr_[lane]; vs1 = sr_[lane + 64];
                    qv = s_q[i];
                }
                if (i >= 2) {
                    int j = i - 1;
                    const float* bcb = bc + (size_t)blk * BCS;
                    float Mv = ld_cohf(bcb + t);
                    float hr = ld_cohf(bcb + 512 + t), hz = ld_cohf(bcb + 1024 + t), hn = ld_cohf(bcb + 1536 + t);
                    float gir = ld_cohf(bcb + 2048 + t), giz = ld_cohf(bcb + 2560 + t), gin = ld_cohf(bcb + 3072 + t);
                    float ir = ld_cohf(bcb + 3584 + t), iz = ld_cohf(bcb + 4096 + t), inn = ld_cohf(bcb + 4608 + t);
                    float ghr = ld_cohf(bcb + 5120 + t), ghz = ld_cohf(bcb + 5632 + t), ghn = ld_cohf(bcb + 6144 + t);
                    float x = feat[(size_t)(blk * NN + j) * DD + t];
                    float r = sigm(ir + hr), z = sigm(iz + hz);
                    float C = (1.f - z) * tanh_(inn + r * hn) + z * Mv;
                    float r2 = sigm(gir + ghr), z2 = sigm(giz + ghz);
                    float P = (1.f - z2) * tanh_(gin + r2 * ghn) + z2 * x;
                    float Hv = C + P;
                    out[(size_t)(blk * NN + j) * DD + t] = Hv;
                    s_red[t] = Hv * wkreg;
                }
                s_u0[t] = 0.f; s_ut[t] = 0.f;
                __syncthreads();
                if (wv == 0) {
                    if (i >= 2) {
                        float p = 0.f;
                        #pragma unroll
                        for (int jj = 0; jj < 8; ++jj) p += s_red[lane + 64 * jj];
                        #pragma unroll
                        for (int off = 32; off; off >>= 1) p += __shfl_down(p, off, 64);
                        if (lane == 0) s_hk[i - 1] = p;
                    }
                    int n2i = lane + 64;
                    float a0 = (lane < i && va0 != 0) ? (qv + s_hk[lane]) : -1e30f;
                    float a1 = (n2i < i && va1 != 0) ? (qv + s_hk[n2i]) : -1e30f;
                    float m = fmaxf(a0, a1);
                    #pragma unroll
                    for (int off = 32; off; off >>= 1) m = fmaxf(m, __shfl_xor(m, off, 64));
                    float e0 = (a0 > -1e29f) ? __expf(a0 - m) : 0.f;
                    float e1 = (a1 > -1e29f) ? __expf(a1 - m) : 0.f;
                    float ss = e0 + e1;
                    #pragma unroll
                    for (int off = 32; off; off >>= 1) ss += __shfl_xor(ss, off, 64);
                    float inv = 1.f / ss;
                    float w0 = e0 * inv, w1 = e1 * inv;
                    s_w[lane] = w0; s_w[n2i] = w1;
                    s_ws[lane] = w0 * (float)vs0;
                    s_ws[n2i] = w1 * (float)vs1;
                }
                __syncthreads();
                {
                    int g = t >> 7, dqb = (t & 127) * 4;
                    const float* Hb = out + (size_t)blk * NN * DD + dqb;
                    f32x4 u0 = {0.f,0.f,0.f,0.f}, ut = {0.f,0.f,0.f,0.f};
                    int n = g;
                    for (; n + 12 < i; n += 16) {
                        f32x4 h0 = *(const f32x4*)(Hb + (size_t)n * DD);
                        f32x4 h1 = *(const f32x4*)(Hb + (size_t)(n + 4) * DD);
                        f32x4 h2 = *(const f32x4*)(Hb + (size_t)(n + 8) * DD);
                        f32x4 h3 = *(const f32x4*)(Hb + (size_t)(n + 12) * DD);
                        u0 += s_ws[n] * h0 + s_ws[n + 4] * h1 + s_ws[n + 8] * h2 + s_ws[n + 12] * h3;
                        ut += s_w[n] * h0 + s_w[n + 4] * h1 + s_w[n + 8] * h2 + s_w[n + 12] * h3;
                    }
                    for (; n < i; n += 4) {
                        f32x4 h0 = *(const f32x4*)(Hb + (size_t)n * DD);
                        u0 += s_ws[n] * h0;
                        ut += s_w[n] * h0;
                    }
                    #pragma unroll
                    for (int e = 0; e < 4; ++e) {
                        atomicAdd(&s_u0[dqb + e], u0[e]);
                        atomicAdd(&s_ut[dqb + e], ut[e]);
                    }
                }
                __syncthreads();
                {
                    int tt = t & 255, sel = t >> 8;
                    float a0 = s_u0[2 * tt], a1 = s_u0[2 * tt + 1];
                    float t0_ = s_ut[2 * tt], t1_ = s_ut[2 * tt + 1];
                    float b0_ = t0_ - a0, b1_ = t1_ - a1;
                    float v0 = sel ? b0_ : a0, v1 = sel ? b1_ : a1;
                    u16 h0 = f2b(v0), h1 = f2b(v1);
                    u16 l0 = f2b(v0 - b2f(h0)), l1 = f2b(v1 - b2f(h1));
                    u32 hw = (u32)h0 | ((u32)h1 << 16);
                    u32 lw = (u32)l0 | ((u32)l1 << 16);
                    u32* ub32 = (u32*)(ub_i + (size_t)blk * 2048);
                    int base = sel * 512;
                    st_cohu32(ub32 + base + tt, hw);
                    st_cohu32(ub32 + base + 256 + tt, lw);
                }
                __syncthreads();
                if (t == 0) st_cohi(flagsA + blk * 32, i);
            }
            if (wv < 4) {
                waitA(flagsA, i, wv);
                gates_merged<false>(ub_i, s_wc, s_gb, bc, blk, wv, lr, lq);
            } else if (wv == 4) {
                x_task(i, featblob, s_wxw, s_xb, bc, blk, 0, lr, lq);
                x_task(i, featblob, s_wxw, s_xb, bc, blk, 1, lr, lq);
                x_task(i, featblob, s_wxw, s_xb, bc, blk, 2, lr, lq);
            } else if (wv == 5) {
                x_task(i, featblob, s_wxw, s_xb, bc, blk, 3, lr, lq);
                x_task(i, featblob, s_wxw, s_xb, bc, blk, 4, lr, lq);
                x_task(i, featblob, s_wxw, s_xb, bc, blk, 5, lr, lq);
            } else if (wv == 6) {
                x_task(i, featblob, s_wxw, s_xb, bc, blk, 6, lr, lq);
                x_task(i, featblob, s_wxw, s_xb, bc, blk, 7, lr, lq);
            } else {
                waitA(flagsA, i, blk & 3);
                m_task<false>(ub_i, WrB, bc, blk, lr, lq);
            }
            gbar_lite(flagsB, i, blk, NBLK, true, blk < BB);
        }
    }

    // ---- final: row 127 ----
    if (blk < BB) {
        if (use_xg) {
            if (wv == 0) ctr_wait(ctrB + (size_t)(NN - 2) * 16, NBLK);
            __syncthreads();
        }
        int j = NN - 1;
        const float* bcb = bc + (size_t)blk * BCS;
        float Mv = ld_cohf(bcb + t);
        float hr = ld_cohf(bcb + 512 + t), hz = ld_cohf(bcb + 1024 + t), hn = ld_cohf(bcb + 1536 + t);
        float gir = ld_cohf(bcb + 2048 + t), giz = ld_cohf(bcb + 2560 + t), gin = ld_cohf(bcb + 3072 + t);
        float ir, iz, inn, ghr, ghz, ghn;
        if (use_xg) {
            const float* xrow = xg + ((size_t)j * 64 + blk) * 3072;
            ir = xrow[t]; iz = xrow[512 + t]; inn = xrow[1024 + t];
            ghr = xrow[1536 + t]; ghz = xrow[2048 + t]; ghn = xrow[2560 + t];
        } else {
            ir = ld_cohf(bcb + 3584 + t); iz = ld_cohf(bcb + 4096 + t); inn = ld_cohf(bcb + 4608 + t);
            ghr = ld_cohf(bcb + 5120 + t); ghz = ld_cohf(bcb + 5632 + t); ghn = ld_cohf(bcb + 6144 + t);
        }
        float x = feat[(size_t)(blk * NN + j) * DD + t];
        float r = sigm(ir + hr), z = sigm(iz + hz);
        float C = (1.f - z) * tanh_(inn + r * hn) + z * Mv;
        float r2 = sigm(gir + ghr), z2 = sigm(giz + ghz);
        float P = (1.f - z2) * tanh_(gin + r2 * ghn) + z2 * x;
        out[(size_t)(blk * NN + j) * DD + t] = C + P;
    }
}

extern "C" void kernel_launch(void* const* d_in, const int* in_sizes, int n_in,
                              void* d_out, int out_size, void* d_ws, size_t ws_size,
                              hipStream_t stream) {
    (void)in_sizes; (void)n_in; (void)out_size;
    const float* feat = (const float*)d_in[0];
    const float* Wi_c = (const float*)d_in[1];
    const float* Wh_c = (const float*)d_in[2];
    const float* bi_c = (const float*)d_in[3];
    const float* bh_c = (const float*)d_in[4];
    const float* Wi_p = (const float*)d_in[5];
    const float* Wh_p = (const float*)d_in[6];
    const float* bi_p = (const float*)d_in[7];
    const float* bh_p = (const float*)d_in[8];
    const float* lin_w = (const float*)d_in[9];
    const float* lin_b = (const float*)d_in[10];
    const float* Wr0 = (const float*)d_in[11];
    const float* Wr1 = (const float*)d_in[12];
    const int* adj = (const int*)d_in[13];
    const int* smask = (const int*)d_in[14];
    float* out = (float*)d_out;

    char* ws = (char*)d_ws;
    size_t off = 0;
    int* sync_ = (int*)(ws + off);      off += 65536;                         // heavy sync + flags + ctrB
    float* q = (float*)(ws + off);      off += (size_t)BB * NN * 4;           // 32 KB
    u16* featblob = (u16*)(ws + off);   off += (size_t)BB * NN * 1024 * 2;    // 16.8 MB
    float* bc = (float*)(ws + off);     off += (size_t)BB * BCS * 4;          // 1.7 MB
    u16* WrB = (u16*)(ws + off);        off += (size_t)512 * 2048 * 2;        // 2 MB
    u16* ublob = (u16*)(ws + off);                                            // ring (or 1 entry)
    size_t ring_bytes = (size_t)(NN - 1) * UBE * 2;                           // 33.3 MB
    size_t xg_bytes = (size_t)NN * 64 * 3072 * 4;                             // 100.7 MB
    int use_ring = (ws_size >= off + ring_bytes) ? 1 : 0;
    float* xg = (float*)(ws + off + ring_bytes);
    int use_xg = (use_ring && ws_size >= off + ring_bytes + xg_bytes) ? 1 : 0;

    (void)hipMemsetAsync(d_ws, 0, 65536, stream);   // zero flags + counters
    hipLaunchKernelGGL(grn_kernel, dim3(NBLK), dim3(NTHR), 0, stream,
                       feat, Wi_c, Wh_c, bi_c, bh_c, Wi_p, Wh_p, bi_p, bh_p,
                       lin_w, lin_b, Wr0, Wr1, adj, smask, out,
                       q, ublob, featblob, bc, WrB, xg, sync_, use_ring, use_xg);
}

// Round 10
// 3405.286 us; speedup vs baseline: 1.1573x; 1.1573x over previous
//
#include <hip/hip_runtime.h>

#define BB 64
#define NN 128
#define DD 512
#define NBLK 128
#define NTHR 512
#define GCOLS 24
#define WCS 2064   // u16 per combined-weight col (padded: ~4-way LDS conflict)
#define WXS 1032   // u16 per x-weight col: [Wh 512 | Wl 512 | pad 8]
#define BCS 6656
#define UBE (BB * 2048)   // u16 per ublob ring entry (256 KB)

typedef unsigned short u16;
typedef unsigned int u32;
typedef unsigned long long u64;
typedef __attribute__((ext_vector_type(8))) __bf16 bf16x8;
typedef __attribute__((ext_vector_type(4))) float f32x4;

#define MFMA16(a, b, c) __builtin_amdgcn_mfma_f32_16x16x32_bf16((a), (b), (c), 0, 0, 0)

__device__ __forceinline__ float b2f(u16 u) {
    union { u32 i; float f; } c; c.i = ((u32)u) << 16; return c.f;
}
__device__ __forceinline__ u16 f2b(float f) {
    union { float f; u32 i; } c; c.f = f;
    return (u16)((c.i + 0x7FFFu + ((c.i >> 16) & 1u)) >> 16);
}
__device__ __forceinline__ float sigm(float x) { return 1.f / (1.f + __expf(-x)); }
__device__ __forceinline__ float tanh_(float x) {
    x = fminf(fmaxf(x, -15.f), 15.f);
    float e = __expf(2.f * x);
    return (e - 1.f) / (e + 1.f);
}

// issue-stall pacing that does NOT advertise idleness to the power manager
// (s_sleep explicitly hints the SMU to downclock; s_nop just stalls issue)
__device__ __forceinline__ void pace() {
    asm volatile("s_nop 7\ns_nop 7" ::: );
}

// ===== agent-coherent (sc1 / L2-bypass) accessors: RELAXED, fence-free =====
__device__ __forceinline__ float ld_cohf(const float* p) {
    return __hip_atomic_load((float*)p, __ATOMIC_RELAXED, __HIP_MEMORY_SCOPE_AGENT);
}
__device__ __forceinline__ void st_cohf(float* p, float v) {
    __hip_atomic_store(p, v, __ATOMIC_RELAXED, __HIP_MEMORY_SCOPE_AGENT);
}
__device__ __forceinline__ void st_cohu32(u32* p, u32 v) {
    __hip_atomic_store(p, v, __ATOMIC_RELAXED, __HIP_MEMORY_SCOPE_AGENT);
}
__device__ __forceinline__ void st_cohi(int* p, int v) {
    __hip_atomic_store(p, v, __ATOMIC_RELAXED, __HIP_MEMORY_SCOPE_AGENT);
}
__device__ __forceinline__ int ld_cohi(int* p) {
    return __hip_atomic_load(p, __ATOMIC_RELAXED, __HIP_MEMORY_SCOPE_AGENT);
}

// ublob load: CACHED = plain dwordx4 (ring entry never stale); else sc1 pair
template<bool CACHED>
__device__ __forceinline__ bf16x8 ldu16(const u16* p) {
    if constexpr (CACHED) {
        return *(const bf16x8*)p;
    } else {
        union { bf16x8 v; u64 q[2]; } u;
        u.q[0] = __hip_atomic_load((u64*)p,     __ATOMIC_RELAXED, __HIP_MEMORY_SCOPE_AGENT);
        u.q[1] = __hip_atomic_load((u64*)p + 1, __ATOMIC_RELAXED, __HIP_MEMORY_SCOPE_AGENT);
        return u.v;
    }
}

// ===== heavy (fenced) barrier — PROLOGUE ONLY =====
__device__ __forceinline__ void gbar(int* sync, int gen, int blk) {
    __syncthreads();
    int* epoch = sync;
    if (blk == 0) {
        const int t = threadIdx.x;
        int done = (t == 0 || t >= NBLK) ? 1 : 0;
        int* myarr = sync + 256 + t * 16;
        int it = 0;
        for (;;) {
            if (!done) {
                int v = ((it & 15) == 15)
                    ? __hip_atomic_load(myarr, __ATOMIC_ACQUIRE, __HIP_MEMORY_SCOPE_AGENT)
                    : __hip_atomic_load(myarr, __ATOMIC_RELAXED, __HIP_MEMORY_SCOPE_AGENT);
                done = (v >= gen);
            }
            ++it;
            if (__syncthreads_and(done)) break;
            __builtin_amdgcn_s_sleep(1);
        }
        if (t == 0) {
            (void)__hip_atomic_load(sync + 256 + 16, __ATOMIC_ACQUIRE, __HIP_MEMORY_SCOPE_AGENT);
            __hip_atomic_store(epoch, gen, __ATOMIC_RELEASE, __HIP_MEMORY_SCOPE_AGENT);
        }
        __syncthreads();
    } else {
        if (threadIdx.x == 0) {
            __hip_atomic_store(sync + 256 + blk * 16, gen, __ATOMIC_RELEASE, __HIP_MEMORY_SCOPE_AGENT);
            int it = 0;
            for (;;) {
                int v = ((it & 15) == 15)
                    ? __hip_atomic_load(epoch, __ATOMIC_ACQUIRE, __HIP_MEMORY_SCOPE_AGENT)
                    : __hip_atomic_load(epoch, __ATOMIC_RELAXED, __HIP_MEMORY_SCOPE_AGENT);
                ++it;
                if (v >= gen) break;
                __builtin_amdgcn_s_sleep(1);
            }
            (void)__hip_atomic_load(epoch, __ATOMIC_ACQUIRE, __HIP_MEMORY_SCOPE_AGENT);
        }
        __syncthreads();
    }
}

// ===== lite flat barrier (pure relaxed polling) — fallback mode only =====
__device__ __forceinline__ void gbar_lite(int* flags, int gen, int blk,
                                          int nsig, bool sig, bool wait) {
    __syncthreads();
    if (sig && threadIdx.x == 0)
        st_cohi(flags + blk * 32, gen);
    if (wait) {
        const int t = threadIdx.x;
        int done = (t >= nsig) ? 1 : 0;
        int* f = flags + t * 32;
        for (;;) {
            if (!done) done = (ld_cohi(f) >= gen);
            if (__syncthreads_and(done)) break;
            __builtin_amdgcn_s_sleep(2);
        }
    }
    asm volatile("" ::: "memory");
    __builtin_amdgcn_sched_barrier(0);
}

// per-WAVE producer wait — BUSY POLL with s_nop pacing (no s_sleep: keeps the
// wave "active" for the clock governor; poll rate is naturally capped by the
// ~200-900cy uncached load latency anyway)
__device__ __forceinline__ void waitA(int* flagsA, int gen, int grp) {
    const int l = threadIdx.x & 63;
    int* f = flagsA + (grp * 16 + (l & 15)) * 32;
    for (;;) {
        int v = ld_cohi(f);
        if (__all(v >= gen)) break;
        pace();
    }
    asm volatile("" ::: "memory");
    __builtin_amdgcn_sched_barrier(0);
}

// per-wave early PhB-completion signal (r7 design): drain own stores, count in
// LDS (monotonic, 5 signalers/iter), 5th wave publishes the block's flagB = i.
__device__ __forceinline__ void sigB(int* flagsB, int* sd, int i, int blk, int lane) {
    asm volatile("s_waitcnt vmcnt(0)" ::: "memory");
    if (lane == 0) {
        int old = atomicAdd(sd, 1);
        if (old == 5 * i - 1)
            st_cohi(flagsB + blk * 32, i);
    }
}

// merged gates GEMM: one wave (rt=0..3) computes BOTH column-tiles (cc=lr, lr+8)
template<bool CACHED>
__device__ __forceinline__ void gates_merged(
    const u16* __restrict__ ub, const u16* s_wc, const float* s_gb,
    float* __restrict__ bc, int blk, int rt, int lr, int lq)
{
    const int cc0 = lr, cc1 = lr + 8;
    const u16* w0 = s_wc + cc0 * WCS;
    const u16* w1 = s_wc + cc1 * WCS;
    const u16* arow = ub + (size_t)(rt * 16 + lr) * 2048;
    f32x4 acc0 = {0.f,0.f,0.f,0.f}, acc1 = {0.f,0.f,0.f,0.f};
    #pragma unroll 4
    for (int c = 0; c < 16; ++c) {
        int kk = c * 32 + lq * 8;
        bf16x8 ah = ldu16<CACHED>(arow + kk);
        bf16x8 al = ldu16<CACHED>(arow + 512 + kk);
        bf16x8 wh0 = *(const bf16x8*)(w0 + kk);
        bf16x8 wl0 = *(const bf16x8*)(w0 + 1024 + kk);
        bf16x8 wh1 = *(const bf16x8*)(w1 + kk);
        bf16x8 wl1 = *(const bf16x8*)(w1 + 1024 + kk);
        acc0 = MFMA16(ah, wh0, acc0); acc0 = MFMA16(al, wh0, acc0); acc0 = MFMA16(ah, wl0, acc0);
        acc1 = MFMA16(ah, wh1, acc1); acc1 = MFMA16(al, wh1, acc1); acc1 = MFMA16(ah, wl1, acc1);
    }
    #pragma unroll 4
    for (int c = 0; c < 16; ++c) {
        int kk = c * 32 + lq * 8;
        bf16x8 ah = ldu16<CACHED>(arow + 1024 + kk);
        bf16x8 al = ldu16<CACHED>(arow + 1536 + kk);
        bf16x8 wh0 = *(const bf16x8*)(w0 + 512 + kk);
        bf16x8 wl0 = *(const bf16x8*)(w0 + 1536 + kk);
        bf16x8 wh1 = *(const bf16x8*)(w1 + 512 + kk);
        bf16x8 wl1 = *(const bf16x8*)(w1 + 1536 + kk);
        acc0 = MFMA16(ah, wh0, acc0); acc0 = MFMA16(al, wh0, acc0); acc0 = MFMA16(ah, wl0, acc0);
        acc1 = MFMA16(ah, wh1, acc1); acc1 = MFMA16(al, wh1, acc1); acc1 = MFMA16(ah, wl1, acc1);
    }
    float b0 = s_gb[cc0], b1 = s_gb[cc1];
    int col0 = blk * GCOLS + cc0, col1 = blk * GCOLS + cc1;
    #pragma unroll
    for (int r = 0; r < 4; ++r) {
        size_t row = (size_t)(rt * 16 + lq * 4 + r) * BCS;
        st_cohf(bc + row + 512 + col0, acc0[r] + b0);
        st_cohf(bc + row + 512 + col1, acc1[r] + b1);
    }
}

// x-gates GEMM core (featblob RO-cached)
__device__ __forceinline__ f32x4 x_core(
    int i, const u16* __restrict__ featblob, const u16* s_wxw,
    int task, int lr, int lq, int* ccO)
{
    const int ct = task & 1, rt = task >> 1;
    const int cc = ct * 8 + lr;
    *ccO = cc;
    const u16* wcol = s_wxw + cc * WXS;
    const u16* arow = featblob + (size_t)(i * 64 + rt * 16 + lr) * 1024;
    f32x4 acc = {0.f,0.f,0.f,0.f};
    #pragma unroll 4
    for (int c = 0; c < 16; ++c) {
        int kk = c * 32 + lq * 8;
        bf16x8 ah = *(const bf16x8*)(arow + kk);
        bf16x8 al = *(const bf16x8*)(arow + 512 + kk);
        bf16x8 wh = *(const bf16x8*)(wcol + kk);
        bf16x8 wl = *(const bf16x8*)(wcol + 512 + kk);
        acc = MFMA16(ah, wh, acc); acc = MFMA16(al, wh, acc); acc = MFMA16(ah, wl, acc);
    }
    return acc;
}

__device__ __forceinline__ void x_task(
    int i, const u16* __restrict__ featblob, const u16* s_wxw, const float* s_xb,
    float* __restrict__ bc, int blk, int task, int lr, int lq)
{
    int cc; f32x4 acc = x_core(i, featblob, s_wxw, task, lr, lq, &cc);
    const int rt = task >> 1;
    const int col = blk * GCOLS + cc;
    float bias = s_xb[cc];
    #pragma unroll
    for (int r = 0; r < 4; ++r)
        st_cohf(bc + (size_t)(rt * 16 + lq * 4 + r) * BCS + 3584 + col, acc[r] + bias);
}

// hoisted variant: plain f32 stores into xg[i][row][col]
__device__ __forceinline__ void x_task_xg(
    int i, const u16* __restrict__ featblob, const u16* s_wxw, const float* s_xb,
    float* __restrict__ xg, int blk, int task, int lr, int lq)
{
    int cc; f32x4 acc = x_core(i, featblob, s_wxw, task, lr, lq, &cc);
    const int rt = task >> 1;
    const int col = blk * GCOLS + cc;
    float bias = s_xb[cc];
    #pragma unroll
    for (int r = 0; r < 4; ++r)
        xg[((size_t)i * 64 + rt * 16 + lq * 4 + r) * 3072 + col] = acc[r] + bias;
}

// M GEMM: 16x16 tile per block
template<bool CACHED>
__device__ __forceinline__ void m_task(
    const u16* __restrict__ ub, const u16* __restrict__ WrB,
    float* __restrict__ bc, int blk, int lr, int lq)
{
    const int ct = blk >> 2, rt = blk & 3;
    const int col = ct * 16 + lr;
    const u16* wcol = WrB + (size_t)col * 2048;
    const u16* arow = ub + (size_t)(rt * 16 + lr) * 2048;
    f32x4 acc = {0.f,0.f,0.f,0.f};
    #pragma unroll 4
    for (int c = 0; c < 16; ++c) {
        int kk = c * 32 + lq * 8;
        bf16x8 a0h = ldu16<CACHED>(arow + kk);
        bf16x8 a0l = ldu16<CACHED>(arow + 512 + kk);
        bf16x8 a1h = ldu16<CACHED>(arow + 1024 + kk);
        bf16x8 a1l = ldu16<CACHED>(arow + 1536 + kk);
        bf16x8 w0h = *(const bf16x8*)(wcol + kk);
        bf16x8 w0l = *(const bf16x8*)(wcol + 512 + kk);
        bf16x8 w1h = *(const bf16x8*)(wcol + 1024 + kk);
        bf16x8 w1l = *(const bf16x8*)(wcol + 1536 + kk);
        acc = MFMA16(a0h, w0h, acc); acc = MFMA16(a0l, w0h, acc); acc = MFMA16(a0h, w0l, acc);
        acc = MFMA16(a1h, w1h, acc); acc = MFMA16(a1l, w1h, acc); acc = MFMA16(a1h, w1l, acc);
    }
    #pragma unroll
    for (int r = 0; r < 4; ++r)
        st_cohf(bc + (size_t)(rt * 16 + lq * 4 + r) * BCS + col, acc[r]);
}

__global__ __launch_bounds__(NTHR) void grn_kernel(
    const float* __restrict__ feat, const float* __restrict__ Wi_c, const float* __restrict__ Wh_c,
    const float* __restrict__ bi_c, const float* __restrict__ bh_c,
    const float* __restrict__ Wi_p, const float* __restrict__ Wh_p,
    const float* __restrict__ bi_p, const float* __restrict__ bh_p,
    const float* __restrict__ lin_w, const float* __restrict__ lin_b,
    const float* __restrict__ Wr0, const float* __restrict__ Wr1,
    const int* __restrict__ adj, const int* __restrict__ smask,
    float* __restrict__ out,
    float* __restrict__ q, u16* __restrict__ ublob,
    u16* __restrict__ featblob, float* __restrict__ bc, u16* __restrict__ WrB,
    float* __restrict__ xg, int* __restrict__ sync, int use_ring, int use_xg)
{
    const int t = threadIdx.x, blk = blockIdx.x;
    const int lane = t & 63, wv = t >> 6;
    const int lr = lane & 15, lq = lane >> 4;
    int gen = 0;
    int* flagsA = sync + 4096;   // per-producer flags, 128B-spaced (value = iteration)
    int* flagsB = sync + 8192;   // per-block PhB-done flags (value = iteration)

    __shared__ u16 s_wc[GCOLS * WCS];
    __shared__ __align__(16) char s_wx_raw[GCOLS * WXS * 2];
    __shared__ float s_u0[DD];
    __shared__ float s_ut[DD];
    __shared__ float s_red[NTHR];
    __shared__ float s_hk[NN];
    __shared__ float s_q[NN];
    __shared__ float s_w[NN];
    __shared__ float s_ws[NN];
    __shared__ float s_gb[GCOLS];
    __shared__ float s_xb[GCOLS];
    __shared__ int s_done;       // monotonic PhB-wave completion counter (5/iter)

    u16* s_wxw = (u16*)s_wx_raw;
    float* s_wgf = (float*)s_wx_raw;
    float* s_pu = (float*)s_wx_raw;               // [3][512] masked partials (xg mode)
    float* s_pt = (float*)(s_wx_raw + 6144);      // [3][512] unmasked partials
    float* s_scal = (float*)(s_wx_raw + 12288);   // m_part, denom_p, anew, snew

    const float wkreg = lin_w[DD + t];

    // ================= Ph0: prologue =================
    for (int rr = 0; rr < 64; ++rr) {
        int gr = blk * 64 + rr;
        int bb_ = gr >> 7, nn_ = gr & 127;
        float x = feat[(size_t)gr * DD + t];
        u16 h = f2b(x);
        u16* dst = featblob + (size_t)(nn_ * 64 + bb_) * 1024;
        dst[t] = h;
        dst[512 + t] = f2b(x - b2f(h));
    }
    for (int cc = 0; cc < 4; ++cc) {
        int c = blk * 4 + cc;
        float w0 = Wr0[(size_t)c * DD + t], w1 = Wr1[(size_t)c * DD + t];
        u16 h0 = f2b(w0), h1 = f2b(w1);
        u16* dst = WrB + (size_t)c * 2048;
        dst[t] = h0; dst[512 + t] = f2b(w0 - b2f(h0));
        dst[1024 + t] = h1; dst[1536 + t] = f2b(w1 - b2f(h1));
    }
    {
        float linb = lin_b[0];
        float wqf[8];
        #pragma unroll
        for (int jj = 0; jj < 8; ++jj) wqf[jj] = lin_w[lane * 8 + jj];
        for (int rr = 0; rr < 8; ++rr) {
            int row = blk * 64 + wv * 8 + rr;
            const float* fp = feat + (size_t)row * DD + lane * 8;
            float p = 0.f;
            #pragma unroll
            for (int jj = 0; jj < 8; ++jj) p += fp[jj] * wqf[jj];
            #pragma unroll
            for (int off = 32; off; off >>= 1) p += __shfl_down(p, off, 64);
            if (lane == 0) q[row] = p + linb;
        }
    }
    {
        int jg0 = blk * GCOLS;
        for (int cc = 0; cc < GCOLS; ++cc) {
            int jg = jg0 + cc;
            const float* src = (jg < 1536) ? (Wh_c + (size_t)jg * DD) : (Wi_p + (size_t)(jg - 1536) * DD);
            s_wgf[t * GCOLS + cc] = src[t];
        }
        if (t < GCOLS) {
            int jg = jg0 + t;
            s_gb[t] = (jg < 1536) ? bh_c[jg] : bi_p[jg - 1536];
            s_xb[t] = (jg < 1536) ? bi_c[jg] : bh_p[jg - 1536];
        }
    }
    __syncthreads();
    {
        float acc0[GCOLS], acc1[GCOLS];
        #pragma unroll
        for (int cc = 0; cc < GCOLS; ++cc) { acc0[cc] = 0.f; acc1[cc] = 0.f; }
        for (int j = 0; j < DD; ++j) {
            float wr0 = Wr0[(size_t)j * DD + t];
            float wr1 = Wr1[(size_t)j * DD + t];
            const float* g = s_wgf + j * GCOLS;
            #pragma unroll
            for (int cc = 0; cc < GCOLS; ++cc) {
                float gv = g[cc];
                acc0[cc] += wr0 * gv;
                acc1[cc] += wr1 * gv;
            }
        }
        __syncthreads();
        #pragma unroll
        for (int cc = 0; cc < GCOLS; ++cc) {
            u16 h0 = f2b(acc0[cc]);
            s_wc[cc * WCS + t] = h0;
            s_wc[cc * WCS + 1024 + t] = f2b(acc0[cc] - b2f(h0));
            u16 h1 = f2b(acc1[cc]);
            s_wc[cc * WCS + 512 + t] = h1;
            s_wc[cc * WCS + 1536 + t] = f2b(acc1[cc] - b2f(h1));
        }
    }
    {
        int jx0 = blk * GCOLS;
        for (int cc = 0; cc < GCOLS; ++cc) {
            int jx = jx0 + cc;
            const float* src = (jx < 1536) ? (Wi_c + (size_t)jx * DD) : (Wh_p + (size_t)(jx - 1536) * DD);
            float w = src[t];
            u16 h = f2b(w);
            s_wxw[cc * WXS + t] = h;
            s_wxw[cc * WXS + 512 + t] = f2b(w - b2f(h));
        }
    }
    gbar(sync, ++gen, blk);

    // ================= Ph0x: x-gates row 0 -> bc; (hoisted) all rows -> xg =====
    x_task(0, featblob, s_wxw, s_xb, bc, blk, wv, lr, lq);
    if (use_xg) {
        for (int ii = 0; ii < NN; ++ii)
            x_task_xg(ii, featblob, s_wxw, s_xb, xg, blk, wv, lr, lq);
    }
    if (blk < BB && t < NN) s_q[t] = q[blk * NN + t];
    gbar(sync, ++gen, blk);

    // ================= Ph1: row 0 init =================
    if (blk < BB) {
        if (use_xg) {
            s_pu[t] = 0.f; s_pu[512 + t] = 0.f; s_pu[1024 + t] = 0.f;
            s_pt[t] = 0.f; s_pt[512 + t] = 0.f; s_pt[1024 + t] = 0.f;
            if (t == 0) {
                s_scal[0] = -1e30f; s_scal[1] = 0.f;
                s_scal[2] = (float)adj[((size_t)blk * NN + 1) * NN + 0];
                s_scal[3] = (float)smask[((size_t)blk * NN + 1) * NN + 0];
            }
        }
        const float* bcb = bc + (size_t)blk * BCS;
        float ir = ld_cohf(bcb + 3584 + t), iz = ld_cohf(bcb + 4096 + t), inn = ld_cohf(bcb + 4608 + t);
        float r = sigm(ir + bh_c[t]), z = sigm(iz + bh_c[512 + t]);
        float C = (1.f - z) * tanh_(inn + r * bh_c[1024 + t]);
        float ghr = ld_cohf(bcb + 5120 + t), ghz = ld_cohf(bcb + 5632 + t), ghn = ld_cohf(bcb + 6144 + t);
        float r2 = sigm(bi_p[t] + ghr), z2 = sigm(bi_p[512 + t] + ghz);
        float n2 = tanh_(bi_p[1024 + t] + r2 * ghn);
        float x = feat[(size_t)(blk * NN) * DD + t];
        float P = (1.f - z2) * n2 + z2 * x;
        float Hv = C + P;
        out[(size_t)(blk * NN) * DD + t] = Hv;
        s_red[t] = Hv * wkreg;
        __syncthreads();
        if (wv == 0) {
            float p = 0.f;
            #pragma unroll
            for (int jj = 0; jj < 8; ++jj) p += s_red[lane + 64 * jj];
            #pragma unroll
            for (int off = 32; off; off >>= 1) p += __shfl_down(p, off, 64);
            if (lane == 0) s_hk[0] = p;
        }
    }
    if (t == 0) s_done = 0;
    gbar(sync, ++gen, blk);

    // ================= main scan =================
    for (int i = 1; i < NN; ++i) {
        u16* ub_i = ublob + (size_t)(use_ring ? (NN - 1 - i) : 0) * UBE;

        if (use_xg) {
            if (blk < BB) {
                // ---- top wait: all 128 blocks' gates+m of iter i-1 done (wave 0 polls,
                // busy/no-sleep; scan waves of PhB(i-1) join at the __syncthreads) ----
                if (i >= 2) {
                    if (wv == 0) {
                        int* fa = flagsB + lane * 32;
                        int* fb = flagsB + (lane + 64) * 32;
                        for (;;) {
                            int va = ld_cohi(fa);
                            int vb = ld_cohi(fb);
                            if (__all((va >= i - 1) && (vb >= i - 1))) break;
                            pace();
                        }
                        asm volatile("" ::: "memory");
                        __builtin_amdgcn_sched_barrier(0);
                    }
                    __syncthreads();
                }
                // ---- PhA ----
                int j = i - 1;
                float Hv;
                if (i >= 2) {
                    const float* bcb = bc + (size_t)blk * BCS;
                    float Mv = ld_cohf(bcb + t);
                    float hr = ld_cohf(bcb + 512 + t), hz = ld_cohf(bcb + 1024 + t), hn = ld_cohf(bcb + 1536 + t);
                    float gir = ld_cohf(bcb + 2048 + t), giz = ld_cohf(bcb + 2560 + t), gin = ld_cohf(bcb + 3072 + t);
                    const float* xrow = xg + ((size_t)j * 64 + blk) * 3072;
                    float ir = xrow[t], iz = xrow[512 + t], inn = xrow[1024 + t];
                    float ghr = xrow[1536 + t], ghz = xrow[2048 + t], ghn = xrow[2560 + t];
                    float x = feat[(size_t)(blk * NN + j) * DD + t];
                    float r = sigm(ir + hr), z = sigm(iz + hz);
                    float C = (1.f - z) * tanh_(inn + r * hn) + z * Mv;
                    float r2 = sigm(gir + ghr), z2 = sigm(giz + ghz);
                    float P = (1.f - z2) * tanh_(gin + r2 * ghn) + z2 * x;
                    Hv = C + P;
                    out[(size_t)(blk * NN + j) * DD + t] = Hv;
                    s_red[t] = Hv * wkreg;
                } else {
                    Hv = out[(size_t)(blk * NN) * DD + t];
                }
                __syncthreads();
                if (wv == 0) {
                    float hk;
                    if (i >= 2) {
                        float p = 0.f;
                        #pragma unroll
                        for (int jj = 0; jj < 8; ++jj) p += s_red[lane + 64 * jj];
                        #pragma unroll
                        for (int off = 32; off; off >>= 1) p += __shfl_down(p, off, 64);
                        if (lane == 0) s_hk[j] = p;
                        hk = p;
                    } else {
                        hk = s_hk[0];
                    }
                    if (lane == 0) {
                        float m_part = s_scal[0], denom_p = s_scal[1];
                        float anew = s_scal[2], snew = s_scal[3];
                        float alpha = s_q[i] + hk;
                        float m = m_part, e_new = 0.f;
                        if (anew != 0.f) { m = fmaxf(m_part, alpha); e_new = __expf(alpha - m); }
                        float scale = __expf(m_part - m);
                        float inv = 1.f / (denom_p * scale + e_new);
                        s_w[0] = scale * inv;
                        s_w[1] = e_new * snew * inv;
                        s_w[2] = e_new * inv;
                    }
                }
                __syncthreads();
                {
                    float u0p = s_pu[t] + s_pu[512 + t] + s_pu[1024 + t];
                    float utp = s_pt[t] + s_pt[512 + t] + s_pt[1024 + t];
                    float CS = s_w[0], C0 = s_w[1], CT = s_w[2];
                    float U0 = u0p * CS + C0 * Hv;
                    float U1 = (utp * CS + CT * Hv) - U0;
                    u16 h0 = f2b(U0); u16 l0 = f2b(U0 - b2f(h0));
                    u16 h1 = f2b(U1); u16 l1 = f2b(U1 - b2f(h1));
                    u32 p0 = (u32)h0 | ((u32)l0 << 16);
                    u32 p1 = (u32)h1 | ((u32)l1 << 16);
                    u32 q0 = (u32)__shfl_xor((int)p0, 1, 64);
                    u32 q1 = (u32)__shfl_xor((int)p1, 1, 64);
                    u32* ub32 = (u32*)(ub_i + (size_t)blk * 2048);
                    int w = t >> 1;
                    if ((t & 1) == 0) {
                        st_cohu32(ub32 + w,       (p0 & 0xFFFFu) | ((q0 & 0xFFFFu) << 16));
                        st_cohu32(ub32 + 256 + w, (p0 >> 16)     | (q0 & 0xFFFF0000u));
                    } else {
                        st_cohu32(ub32 + 512 + w, (q1 & 0xFFFFu) | ((p1 & 0xFFFFu) << 16));
                        st_cohu32(ub32 + 768 + w, (q1 >> 16)     | (p1 & 0xFFFF0000u));
                    }
                }
                __syncthreads();                          // drain ublob sc1 stores
                if (t == 0) st_cohi(flagsA + blk * 32, i);

                // ---- PhB (owner): gates / m / scan; gates+m signal early ----
                if (wv < 4) {
                    waitA(flagsA, i, wv);
                    if (use_ring) gates_merged<true >(ub_i, s_wc, s_gb, bc, blk, wv, lr, lq);
                    else          gates_merged<false>(ub_i, s_wc, s_gb, bc, blk, wv, lr, lq);
                    sigB(flagsB, &s_done, i, blk, lane);
                } else if (wv == 7) {
                    waitA(flagsA, i, blk & 3);
                    if (use_ring) m_task<true >(ub_i, WrB, bc, blk, lr, lq);
                    else          m_task<false>(ub_i, WrB, bc, blk, lr, lq);
                    sigB(flagsB, &s_done, i, blk, lane);
                } else if (i + 1 < NN) {
                    const int ii = i + 1;
                    const int w = wv - 4;
                    const int* ar = adj + (size_t)(blk * NN + ii) * NN;
                    const int* sr = smask + (size_t)(blk * NN + ii) * NN;
                    int a0 = ar[lane], a1 = ar[lane + 64];
                    int s0 = sr[lane], s1 = sr[lane + 64];
                    float qv = s_q[ii];
                    float al0 = (lane < i && a0 != 0) ? (qv + s_hk[lane]) : -1e30f;
                    float al1 = (lane + 64 < i && a1 != 0) ? (qv + s_hk[lane + 64]) : -1e30f;
                    float m = fmaxf(al0, al1);
                    #pragma unroll
                    for (int off = 32; off; off >>= 1) m = fmaxf(m, __shfl_xor(m, off, 64));
                    float e0 = (al0 > -1e29f) ? __expf(al0 - m) : 0.f;
                    float e1 = (al1 > -1e29f) ? __expf(al1 - m) : 0.f;
                    float es0 = e0 * (float)s0, es1 = e1 * (float)s1;
                    const float* Hb = out + (size_t)blk * NN * DD + lane * 8;
                    f32x4 pa = {0.f,0.f,0.f,0.f}, pb = {0.f,0.f,0.f,0.f};
                    f32x4 ta = {0.f,0.f,0.f,0.f}, tb = {0.f,0.f,0.f,0.f};
                    for (int n = w; n < i; n += 3) {
                        float en  = __shfl((n < 64) ? e0 : e1, n & 63, 64);
                        float esn = __shfl((n < 64) ? es0 : es1, n & 63, 64);
                        f32x4 h0 = *(const f32x4*)(Hb + (size_t)n * DD);
                        f32x4 h1 = *(const f32x4*)(Hb + (size_t)n * DD + 4);
                        pa += esn * h0; pb += esn * h1;
                        ta += en * h0;  tb += en * h1;
                    }
                    *(f32x4*)&s_pu[w * 512 + lane * 8]     = pa;
                    *(f32x4*)&s_pu[w * 512 + lane * 8 + 4] = pb;
                    *(f32x4*)&s_pt[w * 512 + lane * 8]     = ta;
                    *(f32x4*)&s_pt[w * 512 + lane * 8 + 4] = tb;
                    if (w == 0) {
                        float ds = e0 + e1;
                        #pragma unroll
                        for (int off = 32; off; off >>= 1) ds += __shfl_xor(ds, off, 64);
                        if (lane == 0) {
                            s_scal[0] = m; s_scal[1] = ds;
                            s_scal[2] = (float)ar[i];
                            s_scal[3] = (float)sr[i];
                        }
                    }
                    if (w == 2) {
                        const float* fp = feat + (size_t)(blk * NN + i) * DD + lane * 8;
                        f32x4 f0 = *(const f32x4*)fp;
                        f32x4 f1 = *(const f32x4*)(fp + 4);
                        const float* xp = xg + ((size_t)i * 64 + blk) * 3072 + lane * 16;
                        float x0 = xp[0], x1 = xp[1024], x2 = xp[2048];
                        asm volatile("" :: "v"(f0), "v"(f1), "v"(x0), "v"(x1), "v"(x2));
                    }
                }
                // no trailing barrier: next iteration's top wait + __syncthreads covers it
            } else {
                // ---- shard blocks: gates + m only; per-wave, no block barrier at all.
                // Safety: waitA(gen i) implies row-owners finished PhA(i) incl. their
                // bc(i-1) reads -> overwriting bc is safe. ----
                if (wv < 4) {
                    waitA(flagsA, i, wv);
                    if (use_ring) gates_merged<true >(ub_i, s_wc, s_gb, bc, blk, wv, lr, lq);
                    else          gates_merged<false>(ub_i, s_wc, s_gb, bc, blk, wv, lr, lq);
                    sigB(flagsB, &s_done, i, blk, lane);
                } else if (wv == 7) {
                    waitA(flagsA, i, blk & 3);
                    if (use_ring) m_task<true >(ub_i, WrB, bc, blk, lr, lq);
                    else          m_task<false>(ub_i, WrB, bc, blk, lr, lq);
                    sigB(flagsB, &s_done, i, blk, lane);
                }
            }
        } else {
            // ================= fallback (non-xg) — round-4 path =================
            if (blk < BB) {
                int va0 = 0, va1 = 0, vs0 = 0, vs1 = 0;
                float qv = 0.f;
                if (wv == 0) {
                    const int* ar_ = adj + (size_t)(blk * NN + i) * NN;
                    const int* sr_ = smask + (size_t)(blk * NN + i) * NN;
                    va0 = ar_[lane]; va1 = ar_[lane + 64];
                    vs0 = sr_[lane]; vs1 = sr_[lane + 64];
                    qv = s_q[i];
                }
                if (i >= 2) {
                    int j = i - 1;
                    const float* bcb = bc + (size_t)blk * BCS;
                    float Mv = ld_cohf(bcb + t);
                    float hr = ld_cohf(bcb + 512 + t), hz = ld_cohf(bcb + 1024 + t), hn = ld_cohf(bcb + 1536 + t);
                    float gir = ld_cohf(bcb + 2048 + t), giz = ld_cohf(bcb + 2560 + t), gin = ld_cohf(bcb + 3072 + t);
                    float ir = ld_cohf(bcb + 3584 + t), iz = ld_cohf(bcb + 4096 + t), inn = ld_cohf(bcb + 4608 + t);
                    float ghr = ld_cohf(bcb + 5120 + t), ghz = ld_cohf(bcb + 5632 + t), ghn = ld_cohf(bcb + 6144 + t);
                    float x = feat[(size_t)(blk * NN + j) * DD + t];
                    float r = sigm(ir + hr), z = sigm(iz + hz);
                    float C = (1.f - z) * tanh_(inn + r * hn) + z * Mv;
                    float r2 = sigm(gir + ghr), z2 = sigm(giz + ghz);
                    float P = (1.f - z2) * tanh_(gin + r2 * ghn) + z2 * x;
                    float Hv = C + P;
                    out[(size_t)(blk * NN + j) * DD + t] = Hv;
                    s_red[t] = Hv * wkreg;
                }
                s_u0[t] = 0.f; s_ut[t] = 0.f;
                __syncthreads();
                if (wv == 0) {
                    if (i >= 2) {
                        float p = 0.f;
                        #pragma unroll
                        for (int jj = 0; jj < 8; ++jj) p += s_red[lane + 64 * jj];
                        #pragma unroll
                        for (int off = 32; off; off >>= 1) p += __shfl_down(p, off, 64);
                        if (lane == 0) s_hk[i - 1] = p;
                    }
                    int n2i = lane + 64;
                    float a0 = (lane < i && va0 != 0) ? (qv + s_hk[lane]) : -1e30f;
                    float a1 = (n2i < i && va1 != 0) ? (qv + s_hk[n2i]) : -1e30f;
                    float m = fmaxf(a0, a1);
                    #pragma unroll
                    for (int off = 32; off; off >>= 1) m = fmaxf(m, __shfl_xor(m, off, 64));
                    float e0 = (a0 > -1e29f) ? __expf(a0 - m) : 0.f;
                    float e1 = (a1 > -1e29f) ? __expf(a1 - m) : 0.f;
                    float ss = e0 + e1;
                    #pragma unroll
                    for (int off = 32; off; off >>= 1) ss += __shfl_xor(ss, off, 64);
                    float inv = 1.f / ss;
                    float w0 = e0 * inv, w1 = e1 * inv;
                    s_w[lane] = w0; s_w[n2i] = w1;
                    s_ws[lane] = w0 * (float)vs0;
                    s_ws[n2i] = w1 * (float)vs1;
                }
                __syncthreads();
                {
                    int g = t >> 7, dqb = (t & 127) * 4;
                    const float* Hb = out + (size_t)blk * NN * DD + dqb;
                    f32x4 u0 = {0.f,0.f,0.f,0.f}, ut = {0.f,0.f,0.f,0.f};
                    int n = g;
                    for (; n + 12 < i; n += 16) {
                        f32x4 h0 = *(const f32x4*)(Hb + (size_t)n * DD);
                        f32x4 h1 = *(const f32x4*)(Hb + (size_t)(n + 4) * DD);
                        f32x4 h2 = *(const f32x4*)(Hb + (size_t)(n + 8) * DD);
                        f32x4 h3 = *(const f32x4*)(Hb + (size_t)(n + 12) * DD);
                        u0 += s_ws[n] * h0 + s_ws[n + 4] * h1 + s_ws[n + 8] * h2 + s_ws[n + 12] * h3;
                        ut += s_w[n] * h0 + s_w[n + 4] * h1 + s_w[n + 8] * h2 + s_w[n + 12] * h3;
                    }
                    for (; n < i; n += 4) {
                        f32x4 h0 = *(const f32x4*)(Hb + (size_t)n * DD);
                        u0 += s_ws[n] * h0;
                        ut += s_w[n] * h0;
                    }
                    #pragma unroll
                    for (int e = 0; e < 4; ++e) {
                        atomicAdd(&s_u0[dqb + e], u0[e]);
                        atomicAdd(&s_ut[dqb + e], ut[e]);
                    }
                }
                __syncthreads();
                {
                    int tt = t & 255, sel = t >> 8;
                    float a0 = s_u0[2 * tt], a1 = s_u0[2 * tt + 1];
                    float t0_ = s_ut[2 * tt], t1_ = s_ut[2 * tt + 1];
                    float b0_ = t0_ - a0, b1_ = t1_ - a1;
                    float v0 = sel ? b0_ : a0, v1 = sel ? b1_ : a1;
                    u16 h0 = f2b(v0), h1 = f2b(v1);
                    u16 l0 = f2b(v0 - b2f(h0)), l1 = f2b(v1 - b2f(h1));
                    u32 hw = (u32)h0 | ((u32)h1 << 16);
                    u32 lw = (u32)l0 | ((u32)l1 << 16);
                    u32* ub32 = (u32*)(ub_i + (size_t)blk * 2048);
                    int base = sel * 512;
                    st_cohu32(ub32 + base + tt, hw);
                    st_cohu32(ub32 + base + 256 + tt, lw);
                }
                __syncthreads();
                if (t == 0) st_cohi(flagsA + blk * 32, i);
            }
            if (wv < 4) {
                waitA(flagsA, i, wv);
                gates_merged<false>(ub_i, s_wc, s_gb, bc, blk, wv, lr, lq);
            } else if (wv == 4) {
                x_task(i, featblob, s_wxw, s_xb, bc, blk, 0, lr, lq);
                x_task(i, featblob, s_wxw, s_xb, bc, blk, 1, lr, lq);
                x_task(i, featblob, s_wxw, s_xb, bc, blk, 2, lr, lq);
            } else if (wv == 5) {
                x_task(i, featblob, s_wxw, s_xb, bc, blk, 3, lr, lq);
                x_task(i, featblob, s_wxw, s_xb, bc, blk, 4, lr, lq);
                x_task(i, featblob, s_wxw, s_xb, bc, blk, 5, lr, lq);
            } else if (wv == 6) {
                x_task(i, featblob, s_wxw, s_xb, bc, blk, 6, lr, lq);
                x_task(i, featblob, s_wxw, s_xb, bc, blk, 7, lr, lq);
            } else {
                waitA(flagsA, i, blk & 3);
                m_task<false>(ub_i, WrB, bc, blk, lr, lq);
            }
            gbar_lite(flagsB, i, blk, NBLK, true, blk < BB);
        }
    }

    // ---- final: row 127 ----
    if (blk < BB) {
        if (use_xg) {
            if (wv == 0) {
                int* fa = flagsB + lane * 32;
                int* fb = flagsB + (lane + 64) * 32;
                for (;;) {
                    int va = ld_cohi(fa);
                    int vb = ld_cohi(fb);
                    if (__all((va >= NN - 1) && (vb >= NN - 1))) break;
                    pace();
                }
                asm volatile("" ::: "memory");
                __builtin_amdgcn_sched_barrier(0);
            }
            __syncthreads();
        }
        int j = NN - 1;
        const float* bcb = bc + (size_t)blk * BCS;
        float Mv = ld_cohf(bcb + t);
        float hr = ld_cohf(bcb + 512 + t), hz = ld_cohf(bcb + 1024 + t), hn = ld_cohf(bcb + 1536 + t);
        float gir = ld_cohf(bcb + 2048 + t), giz = ld_cohf(bcb + 2560 + t), gin = ld_cohf(bcb + 3072 + t);
        float ir, iz, inn, ghr, ghz, ghn;
        if (use_xg) {
            const float* xrow = xg + ((size_t)j * 64 + blk) * 3072;
            ir = xrow[t]; iz = xrow[512 + t]; inn = xrow[1024 + t];
            ghr = xrow[1536 + t]; ghz = xrow[2048 + t]; ghn = xrow[2560 + t];
        } else {
            ir = ld_cohf(bcb + 3584 + t); iz = ld_cohf(bcb + 4096 + t); inn = ld_cohf(bcb + 4608 + t);
            ghr = ld_cohf(bcb + 5120 + t); ghz = ld_cohf(bcb + 5632 + t); ghn = ld_cohf(bcb + 6144 + t);
        }
        float x = feat[(size_t)(blk * NN + j) * DD + t];
        float r = sigm(ir + hr), z = sigm(iz + hz);
        float C = (1.f - z) * tanh_(inn + r * hn) + z * Mv;
        float r2 = sigm(gir + ghr), z2 = sigm(giz + ghz);
        float P = (1.f - z2) * tanh_(gin + r2 * ghn) + z2 * x;
        out[(size_t)(blk * NN + j) * DD + t] = C + P;
    }
}

extern "C" void kernel_launch(void* const* d_in, const int* in_sizes, int n_in,
                              void* d_out, int out_size, void* d_ws, size_t ws_size,
                              hipStream_t stream) {
    (void)in_sizes; (void)n_in; (void)out_size;
    const float* feat = (const float*)d_in[0];
    const float* Wi_c = (const float*)d_in[1];
    const float* Wh_c = (const float*)d_in[2];
    const float* bi_c = (const float*)d_in[3];
    const float* bh_c = (const float*)d_in[4];
    const float* Wi_p = (const float*)d_in[5];
    const float* Wh_p = (const float*)d_in[6];
    const float* bi_p = (const float*)d_in[7];
    const float* bh_p = (const float*)d_in[8];
    const float* lin_w = (const float*)d_in[9];
    const float* lin_b = (const float*)d_in[10];
    const float* Wr0 = (const float*)d_in[11];
    const float* Wr1 = (const float*)d_in[12];
    const int* adj = (const int*)d_in[13];
    const int* smask = (const int*)d_in[14];
    float* out = (float*)d_out;

    char* ws = (char*)d_ws;
    size_t off = 0;
    int* sync_ = (int*)(ws + off);      off += 65536;                         // heavy sync + flags
    float* q = (float*)(ws + off);      off += (size_t)BB * NN * 4;           // 32 KB
    u16* featblob = (u16*)(ws + off);   off += (size_t)BB * NN * 1024 * 2;    // 16.8 MB
    float* bc = (float*)(ws + off);     off += (size_t)BB * BCS * 4;          // 1.7 MB
    u16* WrB = (u16*)(ws + off);        off += (size_t)512 * 2048 * 2;        // 2 MB
    u16* ublob = (u16*)(ws + off);                                            // ring (or 1 entry)
    size_t ring_bytes = (size_t)(NN - 1) * UBE * 2;                           // 33.3 MB
    size_t xg_bytes = (size_t)NN * 64 * 3072 * 4;                             // 100.7 MB
    int use_ring = (ws_size >= off + ring_bytes) ? 1 : 0;
    float* xg = (float*)(ws + off + ring_bytes);
    int use_xg = (use_ring && ws_size >= off + ring_bytes + xg_bytes) ? 1 : 0;

    (void)hipMemsetAsync(d_ws, 0, 65536, stream);   // zero flags
    hipLaunchKernelGGL(grn_kernel, dim3(NBLK), dim3(NTHR), 0, stream,
                       feat, Wi_c, Wh_c, bi_c, bh_c, Wi_p, Wh_p, bi_p, bh_p,
                       lin_w, lin_b, Wr0, Wr1, adj, smask, out,
                       q, ublob, featblob, bc, WrB, xg, sync_, use_ring, use_xg);
}